// Round 5
// baseline (236.656 us; speedup 1.0000x reference)
//
#include <hip/hip_runtime.h>

#define IMG 512
#define WT 64     // w-tile (lanes)
#define HT 64     // h-tile per workgroup
#define NT 256    // threads per workgroup (4 waves)
#define HC (NT / WT)      // 4 h-chunks
#define HPER (HT / HC)    // 16 samples per thread
#define TILE_FLOATS 9216  // 36 KB -> 4 WG/CU; worst case (ny+1)*pitch <= 95*95 = 9025

__global__ void radon_zero(float* __restrict__ out, int n) {
    int i = blockIdx.x * blockDim.x + threadIdx.x;
    if (i < n) out[i] = 0.0f;
}

__global__ __launch_bounds__(NT) void radon_lds(
    const float* __restrict__ x, const float* __restrict__ theta,
    float* __restrict__ out, int N, int A)
{
    __shared__ float tile[TILE_FLOATS];
    int a  = blockIdx.z % A;
    int n  = blockIdx.z / A;
    int w0 = blockIdx.x * WT;
    int h0 = blockIdx.y * HT;

    float rad = theta[a] * (3.14159265358979323846f / 180.0f);
    float c = cosf(rad), s = sinf(rad);

    // Sample coords (exact: 255.5*(2/511) == 1):
    //   ix(w,h) =  c*(w-255.5) + s*(h-255.5) + 255.5
    //   iy(w,h) = -s*(w-255.5) + c*(h-255.5) + 255.5
    float u0 = (float)w0 - 255.5f, u1 = u0 + (float)(WT - 1);
    float t0 = (float)h0 - 255.5f, t1 = t0 + (float)(HT - 1);

    float cu0 = c * u0, cu1 = c * u1, st0 = s * t0, st1 = s * t1;
    float su0 = s * u0, su1 = s * u1, ct0 = c * t0, ct1 = c * t1;

    float ixmin = fminf(fminf(cu0 + st0, cu0 + st1), fminf(cu1 + st0, cu1 + st1)) + 255.5f;
    float ixmax = fmaxf(fmaxf(cu0 + st0, cu0 + st1), fmaxf(cu1 + st0, cu1 + st1)) + 255.5f;
    float iymin = fminf(fminf(ct0 - su0, ct0 - su1), fminf(ct1 - su0, ct1 - su1)) + 255.5f;
    float iymax = fmaxf(fmaxf(ct0 - su0, ct0 - su1), fmaxf(ct1 - su0, ct1 - su1)) + 255.5f;

    // bbox with safety margin; +1 col/row for the bilinear +1 tap
    int xmin = (int)floorf(ixmin) - 1;
    int xmax = (int)floorf(ixmax) + 1;
    int ymin = (int)floorf(iymin) - 1;
    int ymax = (int)floorf(iymax) + 1;

    int ox  = max(xmin, 0);
    int xhi = min(xmax + 1, IMG - 1);
    int oy  = max(ymin, 0);
    int yhi = min(ymax + 1, IMG - 1);
    int wx  = xhi - ox + 1;
    int ny  = yhi - oy + 1;
    if (wx <= 0 || ny <= 0) return;   // tile entirely outside image (WG-uniform)

    int pitch = (wx + 1) | 1;         // >= wx+1 and odd (bank-conflict-free rows)

    // ---- stage bbox into LDS, zero-padding cols [wx,pitch) and row ny ----
    // Every location the sample loop can read is initialized (NaN-safe).
    const float* __restrict__ img = x + (size_t)n * (IMG * IMG);
    int lane = threadIdx.x & 63;
    int wv   = threadIdx.x >> 6;      // 4 waves
    for (int yy = wv; yy < ny; yy += HC) {
        const float* __restrict__ src = img + (size_t)(oy + yy) * IMG + ox;
        float* __restrict__ dst = tile + yy * pitch;
        for (int xx = lane; xx < pitch; xx += 64)
            dst[xx] = (xx < wx) ? src[xx] : 0.0f;
    }
    for (int xx = threadIdx.x; xx < pitch; xx += NT)
        tile[ny * pitch + xx] = 0.0f;
    __syncthreads();

    bool interior = (xmin >= 0) && (xmax + 1 <= IMG - 1) &&
                    (ymin >= 0) && (ymax + 1 <= IMG - 1);

    // ---- compute ----
    int w = w0 + lane;
    float u   = (float)w - 255.5f;
    float fxb = fmaf(c,  u, 255.5f - (float)ox);  // + s*t per sample (local coords)
    float fyb = fmaf(-s, u, 255.5f - (float)oy);  // + c*t per sample

    int wxm1 = wx - 1;
    int nym1 = ny - 1;
    int hstart = h0 + wv * HPER;

    float acc0 = 0.0f, acc1 = 0.0f;
    if (interior) {
        // all 4 taps of every sample are valid texels inside the staged bbox
        #pragma unroll
        for (int i = 0; i < HPER; ++i) {
            float t  = (float)(hstart + i) - 255.5f;
            float fx = fmaf(s, t, fxb);   // >= 1 in interior tiles
            float fy = fmaf(c, t, fyb);
            int jx = (int)fx;             // trunc == floor (nonneg)
            int jy = (int)fy;
            float wx1 = fx - (float)jx;
            float wy1 = fy - (float)jy;
            float wx0 = 1.0f - wx1, wy0 = 1.0f - wy1;

            const float* __restrict__ p0 = tile + (jy * pitch + jx);
            float v00 = p0[0];
            float v01 = p0[1];
            float v10 = p0[pitch];
            float v11 = p0[pitch + 1];

            acc0 = fmaf(wy0, fmaf(wx1, v01, wx0 * v00), acc0);
            acc1 = fmaf(wy1, fmaf(wx1, v11, wx0 * v10), acc1);
        }
    } else {
        #pragma unroll
        for (int i = 0; i < HPER; ++i) {
            float t  = (float)(hstart + i) - 255.5f;
            float fx = fmaf(s, t, fxb);
            float fy = fmaf(c, t, fyb);

            float flx = floorf(fx), fly = floorf(fy);
            float wx1 = fx - flx,   wy1 = fy - fly;
            float wx0 = 1.0f - wx1, wy0 = 1.0f - wy1;

            int jx = (int)flx, jy = (int)fly;
            int gx = jx + ox,  gy = jy + oy;   // global coords of the floor tap

            // zero-pad border, keeping the fixed pair-read valid:
            //  gx == -1: the x1 tap (global col 0) sits in local slot 0.
            //  gx == 511: slot+1 is the zero-filled pad column.
            float nwx0 = ((unsigned)gx <= 511u) ? wx0 : ((gx == -1) ? wx1 : 0.0f);
            float nwx1 = ((unsigned)gx <= 510u) ? wx1 : 0.0f;
            float nwy0 = ((unsigned)gy <= 511u) ? wy0 : ((gy == -1) ? wy1 : 0.0f);
            float nwy1 = ((unsigned)gy <= 510u) ? wy1 : 0.0f;

            int lx = min(max(jx, 0), wxm1);
            int ly = min(max(jy, 0), nym1);

            const float* __restrict__ p0 = tile + (ly * pitch + lx);
            float v00 = p0[0];
            float v01 = p0[1];          // col lx+1 <= wx: staged or zero pad
            float v10 = p0[pitch];      // row ly+1 <= ny: staged or zero row
            float v11 = p0[pitch + 1];

            acc0 = fmaf(nwy0, fmaf(nwx1, v01, nwx0 * v00), acc0);
            acc1 = fmaf(nwy1, fmaf(nwx1, v11, nwx0 * v10), acc1);
        }
    }
    float acc = acc0 + acc1;

    // ---- reduce the HC partials per w, one atomic per (w, h-tile) ----
    __syncthreads();                 // all tile reads done
    tile[threadIdx.x] = acc;
    __syncthreads();
    if (threadIdx.x < WT) {
        float r = 0.0f;
        #pragma unroll
        for (int k = 0; k < HC; ++k) r += tile[k * WT + threadIdx.x];
        atomicAdd(&out[((size_t)n * IMG + w0 + threadIdx.x) * A + a], r);
    }
}

extern "C" void kernel_launch(void* const* d_in, const int* in_sizes, int n_in,
                              void* d_out, int out_size, void* d_ws, size_t ws_size,
                              hipStream_t stream) {
    const float* x     = (const float*)d_in[0];
    const float* theta = (const float*)d_in[1];
    float* out = (float*)d_out;

    int A = in_sizes[1];                   // 180
    int N = in_sizes[0] / (IMG * IMG);     // 2

    int total_out = N * IMG * A;           // 184320
    radon_zero<<<(total_out + 255) / 256, 256, 0, stream>>>(out, total_out);

    dim3 grid(IMG / WT, IMG / HT, N * A);  // 8 x 8 x 360
    radon_lds<<<grid, NT, 0, stream>>>(x, theta, out, N, A);
}

// Round 6
// 165.689 us; speedup vs baseline: 1.4283x; 1.4283x over previous
//
#include <hip/hip_runtime.h>

#define IMG   512
#define WT    64           // w-tile (lanes)
#define HT    64           // h-tile per workgroup
#define NT    512          // 8 waves
#define HC    8            // h-chunks (one per wave)
#define HPER  8            // HT/HC samples per thread
#define ROWS  96           // staged rows (worst-case span 63*sqrt(2)+4 ~ 94)
#define TILE_FLOATS (ROWS * 97)   // 9312 floats = 36.4 KB -> 4 WG/CU = 32 waves

__global__ void radon_zero(float* __restrict__ out, int n) {
    int i = blockIdx.x * blockDim.x + threadIdx.x;
    if (i < n) out[i] = 0.0f;
}

// Uniform inner loop: image pre-embedded in zeros inside the LDS tile, so
// zero-pad border handling is implicit (tap value 0 == weight-masked tap).
// PITCH is compile-time so the 4 taps become 2x ds_read2_b32 (offsets 0/1
// and PITCH/PITCH+1). PITCH chosen per angle so bank = (jx +- jy) mod 32
// has lane-step |c|+|s| >= 1 -> conflict-free for every theta.
template<int PITCH>
__device__ __forceinline__ float sample_chain(const float* __restrict__ tile,
                                              float fx, float fy, float s, float c) {
    float acc0 = 0.0f, acc1 = 0.0f;
    #pragma unroll
    for (int i = 0; i < HPER; ++i) {
        int jx = (int)fx;              // fx >= 1: trunc == floor
        int jy = (int)fy;
        float wx1 = fx - (float)jx;
        float wy1 = fy - (float)jy;
        float wx0 = 1.0f - wx1;
        float wy0 = 1.0f - wy1;
        const float* __restrict__ p = tile + jy * PITCH + jx;
        float v00 = p[0];
        float v01 = p[1];
        float v10 = p[PITCH];
        float v11 = p[PITCH + 1];
        acc0 = fmaf(wy0, fmaf(wx1, v01, wx0 * v00), acc0);
        acc1 = fmaf(wy1, fmaf(wx1, v11, wx0 * v10), acc1);
        fx += s;                       // 8 incremental adds: err < 1e-4 px
        fy += c;
    }
    return acc0 + acc1;
}

__global__ __launch_bounds__(NT, 8) void radon_lds(
    const float* __restrict__ x, const float* __restrict__ theta,
    float* __restrict__ out, int N, int A)
{
    __shared__ float tile[TILE_FLOATS];
    int a  = blockIdx.z % A;
    int n  = blockIdx.z / A;
    int w0 = blockIdx.x * WT;
    int h0 = blockIdx.y * HT;

    float rad = theta[a] * (3.14159265358979323846f / 180.0f);
    float s, c;
    __sincosf(rad, &s, &c);

    // ix(w,h) =  c*u + s*t + 255.5,  iy(w,h) = -s*u + c*t + 255.5
    // with u = w-255.5, t = h-255.5   (exact: 255.5*(2/511) == 1)
    float u0 = (float)w0 - 255.5f, u1 = u0 + (float)(WT - 1);
    float t0 = (float)h0 - 255.5f, t1 = t0 + (float)(HT - 1);

    float cu0 = c * u0, cu1 = c * u1, st0 = s * t0, st1 = s * t1;
    float su0 = s * u0, su1 = s * u1, ct0 = c * t0, ct1 = c * t1;

    float ixmin = fminf(fminf(cu0 + st0, cu0 + st1), fminf(cu1 + st0, cu1 + st1)) + 255.5f;
    float ixmax = fmaxf(fmaxf(cu0 + st0, cu0 + st1), fmaxf(cu1 + st0, cu1 + st1)) + 255.5f;
    float iymin = fminf(fminf(ct0 - su0, ct0 - su1), fminf(ct1 - su0, ct1 - su1)) + 255.5f;
    float iymax = fmaxf(fmaxf(ct0 - su0, ct0 - su1), fmaxf(ct1 - su0, ct1 - su1)) + 255.5f;

    // Unclipped local frame: origin (xmin, ymin); taps fall in
    // jx in [1, dx+2], jy in [1, dy+2]  ->  stage dx+4 cols, dy+4 rows.
    int xmin = (int)floorf(ixmin) - 1;
    int ymin = (int)floorf(iymin) - 1;
    int dx   = (int)floorf(ixmax) - (xmin + 1);
    int dy   = (int)floorf(iymax) - (ymin + 1);

    bool use95 = (c * s >= 0.0f);      // pick pitch so lane bank-step = |c|+|s| >= 1
    int pitch  = use95 ? 95 : 97;
    int nxn = min(dx + 4, pitch);
    int nyn = min(dy + 4, ROWS);

    // ---- stage unclipped bbox; zeros outside the image (NaN-safe, branchless pad) ----
    const float* __restrict__ img = x + (size_t)n * (IMG * IMG);
    int lane = threadIdx.x & 63;
    int wv   = threadIdx.x >> 6;
    for (int yy = wv; yy < nyn; yy += HC) {
        int gy = ymin + yy;
        const float* __restrict__ src = img + (size_t)gy * IMG + xmin;
        float* __restrict__ dst = tile + yy * pitch;
        bool rowok = (unsigned)gy < 512u;
        for (int xx = lane; xx < nxn; xx += 64) {
            int gx = xmin + xx;
            float v = 0.0f;
            if (rowok && (unsigned)gx < 512u) v = src[xx];
            dst[xx] = v;
        }
    }
    __syncthreads();

    // ---- compute: 8 samples along h per thread ----
    float u  = (float)(w0 + lane) - 255.5f;
    float tb = (float)(h0 + wv * HPER) - 255.5f;
    float fxb = fmaf(c,  u, 255.5f - (float)xmin);
    float fyb = fmaf(-s, u, 255.5f - (float)ymin);
    float fx = fmaf(s, tb, fxb);       // local coords, >= 1 by construction
    float fy = fmaf(c, tb, fyb);

    float acc = use95 ? sample_chain<95>(tile, fx, fy, s, c)
                      : sample_chain<97>(tile, fx, fy, s, c);

    // ---- reduce 8 wave-partials per w, one atomic per (w, h-tile) ----
    __syncthreads();                   // all tile reads done
    tile[threadIdx.x] = acc;
    __syncthreads();
    if (threadIdx.x < WT) {
        float r = 0.0f;
        #pragma unroll
        for (int k = 0; k < HC; ++k) r += tile[k * WT + threadIdx.x];
        atomicAdd(&out[((size_t)n * IMG + w0 + threadIdx.x) * A + a], r);
    }
}

extern "C" void kernel_launch(void* const* d_in, const int* in_sizes, int n_in,
                              void* d_out, int out_size, void* d_ws, size_t ws_size,
                              hipStream_t stream) {
    const float* x     = (const float*)d_in[0];
    const float* theta = (const float*)d_in[1];
    float* out = (float*)d_out;

    int A = in_sizes[1];                   // 180
    int N = in_sizes[0] / (IMG * IMG);     // 2

    int total_out = N * IMG * A;           // 184320
    radon_zero<<<(total_out + 255) / 256, 256, 0, stream>>>(out, total_out);

    dim3 grid(IMG / WT, IMG / HT, N * A);  // 8 x 8 x 360
    radon_lds<<<grid, NT, 0, stream>>>(x, theta, out, N, A);
}

// Round 7
// 132.772 us; speedup vs baseline: 1.7824x; 1.2479x over previous
//
#include <hip/hip_runtime.h>

#define IMG   512
#define WT    64           // w-tile (lanes)
#define HT    64           // h-tile per workgroup
#define NT    512          // 8 waves
#define HC    8            // h-chunks (one per wave)
#define HPER  8            // HT/HC samples per thread
#define ROWS  96           // staged rows (worst-case span 63*sqrt(2)+5 ~ 94)
#define PITCH_A 95         // used when c*s >= 0  (95 % 32 == 31: bank ~ jx - jy)
#define PITCH_B 97         // used when c*s <  0  (97 % 32 ==  1: bank ~ jx + jy)
#define TILE_FLOATS (ROWS * PITCH_B + 8)   // 9320 floats = 37.3 KB -> 4 WG/CU

__global__ void radon_zero(float* __restrict__ out, int n) {
    int i = blockIdx.x * blockDim.x + threadIdx.x;
    if (i < n) out[i] = 0.0f;
}

// Direct global->LDS DMA: wave-uniform LDS base, HW adds lane*4; global addr
// is per-lane. No VGPR round trip, no ds_write, ~3 inst per 64-float chunk.
__device__ __forceinline__ void gload_lds4(const float* g, float* l) {
    __builtin_amdgcn_global_load_lds((const __attribute__((address_space(1))) void*)g,
                                     (__attribute__((address_space(3))) void*)l,
                                     4, 0, 0);
}

// Uniform inner loop: image zero-embedded in the LDS tile, so zero-pad border
// handling is implicit. PITCH compile-time -> taps become 2x ds_read2_b32
// (offset pairs 0/1 and PITCH/PITCH+1). PITCH parity (mod 32) chosen per angle
// so the lane-to-lane bank step is |c|+|s| >= 1 -> no systematic conflicts.
template<int PITCH>
__device__ __forceinline__ float sample_chain(const float* __restrict__ tile,
                                              float fx, float fy, float s, float c) {
    float acc = 0.0f;
    #pragma unroll
    for (int i = 0; i < HPER; ++i) {
        float flx = floorf(fx), fly = floorf(fy);
        float wx1 = fx - flx;
        float wy1 = fy - fly;
        int jx = (int)fx;              // fx >= 1: trunc == floor
        int jy = (int)fy;
        const float* __restrict__ p = tile + (__mul24(jy, PITCH) + jx);
        float v00 = p[0];
        float v01 = p[1];
        float v10 = p[PITCH];
        float v11 = p[PITCH + 1];
        float lx0 = fmaf(wx1, v01 - v00, v00);   // lerp form: 7 FLOPs/sample
        float lx1 = fmaf(wx1, v11 - v10, v10);
        acc += fmaf(wy1, lx1 - lx0, lx0);
        fx += s;                       // 8 incremental adds: err < 1e-4 px
        fy += c;
    }
    return acc;
}

__global__ __launch_bounds__(NT, 8) void radon_lds(
    const float* __restrict__ x, const float* __restrict__ theta,
    float* __restrict__ out, int N, int A)
{
    __shared__ float tile[TILE_FLOATS];
    int a  = blockIdx.z % A;
    int n  = blockIdx.z / A;
    int w0 = blockIdx.x * WT;
    int h0 = blockIdx.y * HT;

    float rad = theta[a] * (3.14159265358979323846f / 180.0f);
    float s, c;
    __sincosf(rad, &s, &c);

    // ix(w,h) =  c*u + s*t + 255.5,  iy(w,h) = -s*u + c*t + 255.5
    // with u = w-255.5, t = h-255.5   (exact: 255.5*(2/511) == 1)
    float u0 = (float)w0 - 255.5f, u1 = u0 + (float)(WT - 1);
    float t0 = (float)h0 - 255.5f, t1 = t0 + (float)(HT - 1);

    float cu0 = c * u0, cu1 = c * u1, st0 = s * t0, st1 = s * t1;
    float su0 = s * u0, su1 = s * u1, ct0 = c * t0, ct1 = c * t1;

    float ixmin = fminf(fminf(cu0 + st0, cu0 + st1), fminf(cu1 + st0, cu1 + st1)) + 255.5f;
    float ixmax = fmaxf(fmaxf(cu0 + st0, cu0 + st1), fmaxf(cu1 + st0, cu1 + st1)) + 255.5f;
    float iymin = fminf(fminf(ct0 - su0, ct0 - su1), fminf(ct1 - su0, ct1 - su1)) + 255.5f;
    float iymax = fmaxf(fmaxf(ct0 - su0, ct0 - su1), fmaxf(ct1 - su0, ct1 - su1)) + 255.5f;

    // Unclipped local frame with origin (xmin, ymin): all taps land in
    // jx in [1, dx+2], jy in [1, dy+2] -> stage dx+4 cols, dy+4 rows.
    int xmin = (int)floorf(ixmin) - 1;
    int ymin = (int)floorf(iymin) - 1;
    int dx   = (int)floorf(ixmax) - (xmin + 1);
    int dy   = (int)floorf(iymax) - (ymin + 1);

    bool use95 = (c * s >= 0.0f);
    int pitch  = use95 ? PITCH_A : PITCH_B;
    int nxn = min(dx + 4, pitch);
    int nyn = min(dy + 4, ROWS);

    const float* __restrict__ img = x + (size_t)n * (IMG * IMG);
    int lane = threadIdx.x & 63;
    int wv   = threadIdx.x >> 6;

    bool border = (xmin < 0) | (ymin < 0) | (xmin + nxn > IMG) | (ymin + nyn > IMG);
    if (!border) {
        // ---- interior fast path: pure DMA, no bounds checks ----
        for (int yy = wv; yy < nyn; yy += HC) {
            const float* __restrict__ src = img + (size_t)(ymin + yy) * IMG + xmin;
            float* dst = tile + __mul24(yy, pitch);
            for (int x0 = 0; x0 < nxn; x0 += 64) {
                if (x0 + lane < nxn)
                    gload_lds4(src + x0 + lane, dst + x0);  // LDS base uniform per call
            }
        }
    } else {
        // ---- border: zero-prefill then DMA the image intersection ----
        int total4 = (__mul24(nyn, pitch) + 3) >> 2;
        float4 z = make_float4(0.f, 0.f, 0.f, 0.f);
        for (int i = threadIdx.x; i < total4; i += NT)
            ((float4*)tile)[i] = z;
        __syncthreads();   // zeros visible before DMA overwrites

        int gx0 = max(xmin, 0), gx1 = min(xmin + nxn, IMG);
        int gy0 = max(ymin, 0), gy1 = min(ymin + nyn, IMG);
        int lx0 = gx0 - xmin;          // >= 0
        for (int gy = gy0 + wv; gy < gy1; gy += HC) {
            int yy = gy - ymin;
            const float* __restrict__ src = img + (size_t)gy * IMG;
            float* dst = tile + (__mul24(yy, pitch) + lx0);
            for (int k = 0; gx0 + k < gx1; k += 64) {
                if (gx0 + k + lane < gx1)
                    gload_lds4(src + gx0 + k + lane, dst + k);
            }
        }
    }
    __syncthreads();       // drains vmcnt (compiler emits vmcnt(0) before barrier)

    // ---- compute: 8 samples along h per thread ----
    float u  = (float)(w0 + lane) - 255.5f;
    float tb = (float)(h0 + wv * HPER) - 255.5f;
    float fxb = fmaf(c,  u, 255.5f - (float)xmin);
    float fyb = fmaf(-s, u, 255.5f - (float)ymin);
    float fx = fmaf(s, tb, fxb);       // local coords, >= 1 by construction
    float fy = fmaf(c, tb, fyb);

    float acc = use95 ? sample_chain<PITCH_A>(tile, fx, fy, s, c)
                      : sample_chain<PITCH_B>(tile, fx, fy, s, c);

    // ---- reduce 8 wave-partials per w, one atomic per (w, h-tile) ----
    __syncthreads();                   // all tile reads done
    tile[threadIdx.x] = acc;
    __syncthreads();
    if (threadIdx.x < WT) {
        float r = 0.0f;
        #pragma unroll
        for (int k = 0; k < HC; ++k) r += tile[k * WT + threadIdx.x];
        atomicAdd(&out[((size_t)n * IMG + w0 + threadIdx.x) * A + a], r);
    }
}

extern "C" void kernel_launch(void* const* d_in, const int* in_sizes, int n_in,
                              void* d_out, int out_size, void* d_ws, size_t ws_size,
                              hipStream_t stream) {
    const float* x     = (const float*)d_in[0];
    const float* theta = (const float*)d_in[1];
    float* out = (float*)d_out;

    int A = in_sizes[1];                   // 180
    int N = in_sizes[0] / (IMG * IMG);     // 2

    int total_out = N * IMG * A;           // 184320
    radon_zero<<<(total_out + 255) / 256, 256, 0, stream>>>(out, total_out);

    dim3 grid(IMG / WT, IMG / HT, N * A);  // 8 x 8 x 360
    radon_lds<<<grid, NT, 0, stream>>>(x, theta, out, N, A);
}

// Round 8
// 129.996 us; speedup vs baseline: 1.8205x; 1.0214x over previous
//
#include <hip/hip_runtime.h>

#define IMG   512
#define WT    64           // w-tile (lanes)
#define HT    64           // h-tile per workgroup
#define NT    512          // 8 waves
#define HC    8            // h-chunks (one per wave)
#define HPER  8            // HT/HC samples per thread
#define ROWS  96           // staged rows (worst-case span 63*sqrt(2)+5 ~ 94)
#define PITCH_A 95         // c*s >= 0  (95 % 32 == 31: bank ~ jx - jy)
#define PITCH_B 97         // c*s <  0  (97 % 32 ==  1: bank ~ jx + jy)
#define TILE_FLOATS (ROWS * PITCH_B + 8)   // 9320 floats = 37.3 KB -> 4 WG/CU

__global__ void radon_zero(float* __restrict__ out, int n) {
    int i = blockIdx.x * blockDim.x + threadIdx.x;
    if (i < n) out[i] = 0.0f;
}

// Direct global->LDS DMA: wave-uniform LDS base, HW adds lane*4.
__device__ __forceinline__ void gload_lds4(const float* g, float* l) {
    __builtin_amdgcn_global_load_lds((const __attribute__((address_space(1))) void*)g,
                                     (__attribute__((address_space(3))) void*)l,
                                     4, 0, 0);
}

// One bilinear tap-set fetch + lerp, written so 4 samples' loads can be
// batched by the scheduler (explicit names, full unroll, no loop-carried
// dependence except the final accumulate).
template<int PITCH>
__device__ __forceinline__ float lerp4(const float* __restrict__ tile,
                                       float fx, float fy) {
    int jx = (int)fx;                  // fx,fy >= 1: trunc == floor
    int jy = (int)fy;
    const float* __restrict__ p = tile + (__mul24(jy, PITCH) + jx);
    float v00 = p[0];
    float v01 = p[1];                  // ds_read2_b32 (0,1)
    float v10 = p[PITCH];
    float v11 = p[PITCH + 1];          // ds_read2_b32 (PITCH,PITCH+1)
    float wx1 = fx - (float)jx;
    float wy1 = fy - (float)jy;
    float lx0 = fmaf(wx1, v01 - v00, v00);
    float lx1 = fmaf(wx1, v11 - v10, v10);
    return fmaf(wy1, lx1 - lx0, lx0);
}

template<int PITCH>
__device__ __forceinline__ float sample_chain(const float* __restrict__ tile,
                                              float fx, float fy, float s, float c) {
    float acc0 = 0.0f, acc1 = 0.0f, acc2 = 0.0f, acc3 = 0.0f;
    #pragma unroll
    for (int b = 0; b < HPER / 4; ++b) {
        // batch of 4: independent coords -> 8 ds_read2 issued back-to-back
        float fx0 = fx,       fy0 = fy;
        float fx1 = fx0 + s,  fy1 = fy0 + c;
        float fx2 = fx1 + s,  fy2 = fy1 + c;
        float fx3 = fx2 + s,  fy3 = fy2 + c;
        fx = fx3 + s;  fy = fy3 + c;
        acc0 += lerp4<PITCH>(tile, fx0, fy0);
        acc1 += lerp4<PITCH>(tile, fx1, fy1);
        acc2 += lerp4<PITCH>(tile, fx2, fy2);
        acc3 += lerp4<PITCH>(tile, fx3, fy3);
    }
    return (acc0 + acc1) + (acc2 + acc3);
}

__global__ __launch_bounds__(NT, 8) void radon_lds(
    const float* __restrict__ x, const float* __restrict__ theta,
    float* __restrict__ out, int N, int A)
{
    __shared__ float tile[TILE_FLOATS];
    int a  = blockIdx.z % A;
    int n  = blockIdx.z / A;
    int w0 = blockIdx.x * WT;
    int h0 = blockIdx.y * HT;

    float rad = theta[a] * (3.14159265358979323846f / 180.0f);
    float s, c;
    __sincosf(rad, &s, &c);            // theta in [0,179] deg -> s >= 0

    // Center +- extent bbox (square tile: ex == ey = (|c|+s)*31.5).
    // ix(w,h) = c*u + s*t + 255.5, iy = -s*u + c*t + 255.5; u,t = coord-255.5.
    float uc = (float)w0 + (31.5f - 255.5f);
    float tc = (float)h0 + (31.5f - 255.5f);
    float ex = (fabsf(c) + s) * 31.5f;
    float ixc = fmaf(c, uc, fmaf(s, tc, 255.5f));
    float iyc = fmaf(-s, uc, fmaf(c, tc, 255.5f));

    int xmin = (int)floorf(ixc - ex) - 1;
    int ymin = (int)floorf(iyc - ex) - 1;
    int dx   = (int)floorf(ixc + ex) - (xmin + 1);
    int dy   = (int)floorf(iyc + ex) - (ymin + 1);

    bool use95 = (c * s >= 0.0f);      // pitch parity -> lane bank-step |c|+|s| >= 1
    int pitch  = use95 ? PITCH_A : PITCH_B;
    int nxn = min(dx + 4, pitch);
    int nyn = min(dy + 4, ROWS);

    const float* __restrict__ img = x + (size_t)n * (IMG * IMG);
    int lane = threadIdx.x & 63;
    int wv   = threadIdx.x >> 6;

    bool border = (xmin < 0) | (ymin < 0) | (xmin + nxn > IMG) | (ymin + nyn > IMG);
    if (!border) {
        // ---- interior fast path: pure DMA, no bounds checks ----
        for (int yy = wv; yy < nyn; yy += HC) {
            const float* __restrict__ src = img + (size_t)(ymin + yy) * IMG + xmin;
            float* dst = tile + __mul24(yy, pitch);
            for (int x0 = 0; x0 < nxn; x0 += 64) {
                if (x0 + lane < nxn)
                    gload_lds4(src + x0 + lane, dst + x0);
            }
        }
    } else {
        // ---- border: zero-prefill then DMA the image intersection ----
        int total4 = (__mul24(nyn, pitch) + 3) >> 2;
        float4 z = make_float4(0.f, 0.f, 0.f, 0.f);
        for (int i = threadIdx.x; i < total4; i += NT)
            ((float4*)tile)[i] = z;
        __syncthreads();   // zeros visible before DMA overwrites

        int gx0 = max(xmin, 0), gx1 = min(xmin + nxn, IMG);
        int gy0 = max(ymin, 0), gy1 = min(ymin + nyn, IMG);
        int lx0 = gx0 - xmin;
        for (int gy = gy0 + wv; gy < gy1; gy += HC) {
            int yy = gy - ymin;
            const float* __restrict__ src = img + (size_t)gy * IMG;
            float* dst = tile + (__mul24(yy, pitch) + lx0);
            for (int k = 0; gx0 + k < gx1; k += 64) {
                if (gx0 + k + lane < gx1)
                    gload_lds4(src + gx0 + k + lane, dst + k);
            }
        }
    }
    __syncthreads();       // drains vmcnt before any wave reads the tile

    // ---- compute: 8 samples along h per thread, 4-wide ILP batches ----
    float u  = (float)(w0 + lane) - 255.5f;
    float tb = (float)(h0 + wv * HPER) - 255.5f;
    float fxb = fmaf(c,  u, 255.5f - (float)xmin);
    float fyb = fmaf(-s, u, 255.5f - (float)ymin);
    float fx = fmaf(s, tb, fxb);       // local coords, >= 1 by construction
    float fy = fmaf(c, tb, fyb);

    float acc = use95 ? sample_chain<PITCH_A>(tile, fx, fy, s, c)
                      : sample_chain<PITCH_B>(tile, fx, fy, s, c);

    // ---- reduce 8 wave-partials per w, one atomic per (w, h-tile) ----
    __syncthreads();                   // all tile reads done
    tile[threadIdx.x] = acc;
    __syncthreads();
    if (threadIdx.x < WT) {
        float r = 0.0f;
        #pragma unroll
        for (int k = 0; k < HC; ++k) r += tile[k * WT + threadIdx.x];
        atomicAdd(&out[((size_t)n * IMG + w0 + threadIdx.x) * A + a], r);
    }
}

extern "C" void kernel_launch(void* const* d_in, const int* in_sizes, int n_in,
                              void* d_out, int out_size, void* d_ws, size_t ws_size,
                              hipStream_t stream) {
    const float* x     = (const float*)d_in[0];
    const float* theta = (const float*)d_in[1];
    float* out = (float*)d_out;

    int A = in_sizes[1];                   // 180
    int N = in_sizes[0] / (IMG * IMG);     // 2

    int total_out = N * IMG * A;           // 184320
    radon_zero<<<(total_out + 255) / 256, 256, 0, stream>>>(out, total_out);

    dim3 grid(IMG / WT, IMG / HT, N * A);  // 8 x 8 x 360
    radon_lds<<<grid, NT, 0, stream>>>(x, theta, out, N, A);
}

// Round 9
// 91.578 us; speedup vs baseline: 2.5842x; 1.4195x over previous
//
#include <hip/hip_runtime.h>

#define IMG   512
#define WT    64           // w-tile (lanes)
#define HT    64           // h per strip
#define NSTRIP (IMG / HT)  // 8 strips -> one WG integrates the FULL line
#define NT    512          // 8 waves
#define HC    8            // h-chunks per strip (one per wave)
#define HPER  (HT / HC)    // 8 samples per thread per strip
#define ROWS  96           // staged rows (worst-case strip span 127*0.7071+5 ~ 95)
#define PITCH_A 95         // c*s >= 0  (95 % 32 == 31: bank ~ jx - jy, lane-step |c|+s)
#define PITCH_B 97         // c*s <  0  (97 % 32 ==  1: bank ~ jx + jy, lane-step |c|+s)
#define TILE_FLOATS (ROWS * PITCH_B + 8)   // 9320 floats = 37.3 KB -> 4 WG/CU

// Direct global->LDS DMA: wave-uniform LDS base, HW adds lane*4.
__device__ __forceinline__ void gload_lds4(const float* g, float* l) {
    __builtin_amdgcn_global_load_lds((const __attribute__((address_space(1))) void*)g,
                                     (__attribute__((address_space(3))) void*)l,
                                     4, 0, 0);
}

// single-instruction fractional part (x >= 0 here): replaces floor+sub
__device__ __forceinline__ float vfract(float x) {
    float r;
    asm("v_fract_f32 %0, %1" : "=v"(r) : "v"(x));
    return r;
}

template<int PITCH>
__device__ __forceinline__ float lerp4(const float* __restrict__ tile,
                                       float fx, float fy) {
    int jx = (int)fx;                  // fx,fy >= 1: trunc == floor
    int jy = (int)fy;
    const float* __restrict__ p = tile + (__mul24(jy, PITCH) + jx);
    float v00 = p[0];
    float v01 = p[1];                  // ds_read2_b32 (0,1)
    float v10 = p[PITCH];
    float v11 = p[PITCH + 1];          // ds_read2_b32 (PITCH,PITCH+1)
    float wx1 = vfract(fx);
    float wy1 = vfract(fy);
    float lx0 = fmaf(wx1, v01 - v00, v00);
    float lx1 = fmaf(wx1, v11 - v10, v10);
    return fmaf(wy1, lx1 - lx0, lx0);
}

// Full line integral for one (n, w-tile, angle): loop h-strips, staging each
// strip's rotated bbox into LDS (zero-embedded -> implicit zero padding),
// accumulate 8 samples/thread/strip in registers.
template<int PITCH>
__device__ __forceinline__ void radon_body(
    const float* __restrict__ img, float* __restrict__ tile,
    float* __restrict__ out, float s, float c,
    int n, int a, int w0, int A)
{
    int lane = threadIdx.x & 63;
    int wv   = threadIdx.x >> 6;

    // ix(w,h) = c*u + s*t + 255.5, iy = -s*u + c*t + 255.5; u,t = coord-255.5
    float u   = (float)(w0 + lane) - 255.5f;
    float uc  = (float)w0 + (31.5f - 255.5f);
    float ex  = (fabsf(c) + s) * 31.5f;          // half-extent (square strip)
    float ixc = fmaf(c, uc, fmaf(s, (31.5f - 255.5f), 255.5f));
    float iyc = fmaf(-s, uc, fmaf(c, (31.5f - 255.5f), 255.5f));

    float acc = 0.0f;
    for (int st = 0; st < NSTRIP; ++st) {
        int xmin = (int)floorf(ixc - ex) - 1;
        int ymin = (int)floorf(iyc - ex) - 1;
        int dx   = (int)floorf(ixc + ex) - (xmin + 1);
        int dy   = (int)floorf(iyc + ex) - (ymin + 1);
        int nxn  = min(dx + 4, PITCH);           // 66..95 cols
        int nyn  = min(dy + 4, ROWS);

        if (st > 0) __syncthreads();             // prev strip's reads done

        bool border = (xmin < 0) | (ymin < 0) | (xmin + nxn > IMG) | (ymin + nyn > IMG);
        if (!border) {
            // interior: pure DMA; nxn >= 66 so chunk 0 is unconditional
            for (int yy = wv; yy < nyn; yy += HC) {
                const float* __restrict__ src = img + (size_t)(ymin + yy) * IMG + xmin;
                float* dst = tile + __mul24(yy, PITCH);
                gload_lds4(src + lane, dst);
                if (64 + lane < nxn) gload_lds4(src + 64 + lane, dst + 64);
            }
        } else {
            // border: zero-prefill then DMA the image intersection
            int total4 = (__mul24(nyn, PITCH) + 3) >> 2;
            float4 z = make_float4(0.f, 0.f, 0.f, 0.f);
            for (int i = threadIdx.x; i < total4; i += NT)
                ((float4*)tile)[i] = z;
            __syncthreads();                     // zeros visible before DMA
            int gx0 = max(xmin, 0), gx1 = min(xmin + nxn, IMG);
            int gy0 = max(ymin, 0), gy1 = min(ymin + nyn, IMG);
            int lx0 = gx0 - xmin;
            for (int gy = gy0 + wv; gy < gy1; gy += HC) {
                int yy = gy - ymin;
                const float* __restrict__ src = img + (size_t)gy * IMG;
                float* dst = tile + (__mul24(yy, PITCH) + lx0);
                for (int k = 0; gx0 + k < gx1; k += 64)
                    if (gx0 + k + lane < gx1)
                        gload_lds4(src + gx0 + k + lane, dst + k);
            }
        }
        __syncthreads();                         // DMA drained (vmcnt0 + barrier)

        // 8 samples along h, 4-wide batches
        float tb = (float)(st * HT + wv * HPER) - 255.5f;
        float fx = fmaf(s, tb, fmaf(c,  u, 255.5f - (float)xmin));
        float fy = fmaf(c, tb, fmaf(-s, u, 255.5f - (float)ymin));
        #pragma unroll
        for (int b = 0; b < HPER / 4; ++b) {
            float fx0 = fx,       fy0 = fy;
            float fx1 = fx0 + s,  fy1 = fy0 + c;
            float fx2 = fx1 + s,  fy2 = fy1 + c;
            float fx3 = fx2 + s,  fy3 = fy2 + c;
            fx = fx3 + s;  fy = fy3 + c;
            acc += lerp4<PITCH>(tile, fx0, fy0);
            acc += lerp4<PITCH>(tile, fx1, fy1);
            acc += lerp4<PITCH>(tile, fx2, fy2);
            acc += lerp4<PITCH>(tile, fx3, fy3);
        }

        ixc += s * (float)HT;                    // strip center advances along t
        iyc += c * (float)HT;
    }

    // reduce 8 wave-partials per w; each output written exactly once (no atomics)
    __syncthreads();
    tile[threadIdx.x] = acc;
    __syncthreads();
    if (threadIdx.x < WT) {
        float r = 0.0f;
        #pragma unroll
        for (int k = 0; k < HC; ++k) r += tile[k * WT + threadIdx.x];
        out[((size_t)n * IMG + w0 + threadIdx.x) * A + a] = r;
    }
}

__global__ __launch_bounds__(NT, 8) void radon_lds(
    const float* __restrict__ x, const float* __restrict__ theta,
    float* __restrict__ out, int N, int A)
{
    __shared__ float tile[TILE_FLOATS];
    int a  = blockIdx.z % A;
    int n  = blockIdx.z / A;
    int w0 = blockIdx.x * WT;

    float rad = theta[a] * (3.14159265358979323846f / 180.0f);
    float s, c;
    __sincosf(rad, &s, &c);            // theta in [0,179] deg -> s >= 0

    const float* __restrict__ img = x + (size_t)n * (IMG * IMG);
    if (c * s >= 0.0f)
        radon_body<PITCH_A>(img, tile, out, s, c, n, a, w0, A);
    else
        radon_body<PITCH_B>(img, tile, out, s, c, n, a, w0, A);
}

extern "C" void kernel_launch(void* const* d_in, const int* in_sizes, int n_in,
                              void* d_out, int out_size, void* d_ws, size_t ws_size,
                              hipStream_t stream) {
    const float* x     = (const float*)d_in[0];
    const float* theta = (const float*)d_in[1];
    float* out = (float*)d_out;

    int A = in_sizes[1];                   // 180
    int N = in_sizes[0] / (IMG * IMG);     // 2

    dim3 grid(IMG / WT, 1, N * A);         // 8 x 1 x 360 = 2880 WGs
    radon_lds<<<grid, NT, 0, stream>>>(x, theta, out, N, A);
}